// Round 9
// baseline (127.206 us; speedup 1.0000x reference)
//
#include <hip/hip_runtime.h>

typedef short s16;
typedef unsigned short us16;
typedef __attribute__((ext_vector_type(8))) short s16x8;
typedef __attribute__((ext_vector_type(16))) float f32x16;

#define TOKENS 2048
#define INF    4096   // n_codes * 8
#define OUTF   4096   // m
#define GK     4096

// float -> bf16 round-to-nearest-even
__device__ __forceinline__ us16 f2bf(float f) {
    union { float f; unsigned u; } v; v.f = f;
    unsigned r = v.u + 0x7FFFu + ((v.u >> 16) & 1u);
    return (us16)(r >> 16);
}
__device__ __forceinline__ float bf2f(us16 u) {
    unsigned x = ((unsigned)u) << 16;
    float f; __builtin_memcpy(&f, &x, 4);
    return f;
}

// ---------------------------------------------------------------------------
// FWHT-16 fully in registers
// ---------------------------------------------------------------------------
__device__ __forceinline__ void fwht16(float v[16]) {
#pragma unroll
    for (int s = 1; s < 16; s <<= 1)
#pragma unroll
        for (int j = 0; j < 16; ++j)
            if (!(j & s)) {
                float a = v[j], b = v[j + s];
                v[j]     = a + b;
                v[j + s] = a - b;
            }
}

// ---------------------------------------------------------------------------
// Kernel 1 (merged): blocks [0,2048): y = bf16(FWHT(x*SU)/64)  (radix-16^3)
//                    blocks [2048, 10240): decompress E8P -> W (bf16)
// ---------------------------------------------------------------------------
__global__ __launch_bounds__(256) void k_pre(const float* __restrict__ X,
                                             const float* __restrict__ SU,
                                             us16* __restrict__ Y,
                                             const int* __restrict__ Q,
                                             const void* __restrict__ gridraw,
                                             us16* __restrict__ W) {
    __shared__ float s[4096 + 256];
    const int tid = threadIdx.x;

    if (blockIdx.x < TOKENS) {
        const int row = blockIdx.x;
        const int hi = tid >> 4, lo = tid & 15;
        float v[16];
        const float* xr = X + (size_t)row * INF;

#pragma unroll
        for (int j = 0; j < 16; ++j) v[j] = xr[j * 256 + tid] * SU[j * 256 + tid];
        fwht16(v);
#pragma unroll
        for (int j = 0; j < 16; ++j) s[272 * j + 17 * hi + lo] = v[j];
        __syncthreads();

#pragma unroll
        for (int j = 0; j < 16; ++j) v[j] = s[272 * hi + 17 * j + lo];
        fwht16(v);
#pragma unroll
        for (int j = 0; j < 16; ++j) s[272 * hi + 17 * j + lo] = v[j];
        __syncthreads();

        const int base = 272 * hi + 17 * lo;
#pragma unroll
        for (int j = 0; j < 16; ++j) v[j] = s[base + j];
        fwht16(v);

        s16x8 o0, o1;
#pragma unroll
        for (int j = 0; j < 8; ++j) {
            o0[j] = (s16)f2bf(v[j]     * 0.015625f);
            o1[j] = (s16)f2bf(v[j + 8] * 0.015625f);
        }
        s16x8* out = reinterpret_cast<s16x8*>(Y + (size_t)row * INF + tid * 16);
        out[0] = o0; out[1] = o1;
    } else {
        float (*gT)[256] = (float(*)[256])s;
        int* gOdd = (int*)(s + 2048);

        const unsigned short* gu = (const unsigned short*)gridraw;
        const float*          gf = (const float*)gridraw;
        const unsigned short  p0 = gu[0];

        float sum = 0.f;
#pragma unroll
        for (int j = 0; j < 8; ++j) {
            float v;
            if (p0 == 0x3800) {                       // float16
                unsigned short u = gu[tid * 8 + j];
                _Float16 hv; __builtin_memcpy(&hv, &u, 2);
                v = (float)hv;
            } else if (p0 == 0x3F00) {                // bfloat16
                v = bf2f(gu[tid * 8 + j]);
            } else {                                  // float32
                v = gf[tid * 8 + j];
            }
            gT[j][tid] = v;
            sum += v;
        }
        gOdd[tid] = ((int)(sum + 0.5f)) & 1;
        __syncthreads();

        const int code = (blockIdx.x - TOKENS) * 256 + tid;
        const int q        = Q[code];
        const int absIdx   = (q >> 8) & 255;
        const int signBits = (q >> 1) & 127;
        const float shift  = (q & 1) ? 0.25f : -0.25f;
        const int neg0 = (__popc(signBits) ^ gOdd[absIdx]) & 1;

        s16x8 o;
        o[0] = (s16)f2bf(gT[0][absIdx] * (1.0f - 2.0f * (float)neg0) + shift);
#pragma unroll
        for (int i = 1; i < 8; ++i) {
            float sg = 1.0f - 2.0f * (float)((signBits >> (i - 1)) & 1);
            o[i] = (s16)f2bf(gT[i][absIdx] * sg + shift);
        }
        *reinterpret_cast<s16x8*>(W + (size_t)code * 8) = o;
    }
}

// ---------------------------------------------------------------------------
// Kernel 2: GEMM  z[t][j] = sum_k y[t][k] * W[j][k]  (NT, K-major, bf16)
// 256x256 tile, BK=64, 8 waves (2Mx4N), wave tile 128x64, split-K templated.
// mfma_f32_32x32x16_bf16 (half the MFMA instrs of 16x16x32, +20% peak rate).
// r6 single-barrier loop: all ds_reads + 32 MFMA compiler-interleaved, ONE
// __syncthreads per K-tile (drains 1-tile-old stage loads ~free), then
// STAGE(t+2) into the just-freed buffer. gload_lds(16B), chunk-XOR swizzle
// (inverse-swizzled global source, swizzled ds_read). Bijective XCD swizzle.
// A-frag: row=lane&31, k=(lane>>5)*8+j. C/D: col=lane&31,
// row=(reg&3)+8*(reg>>2)+4*(lane>>5)  [m74/m101].
// ---------------------------------------------------------------------------
#define BM 256
#define BN 256
#define BK 64

template<int KSPLIT>
__global__ __launch_bounds__(512, 1) void k_gemm(const us16* __restrict__ A,
                                                 const us16* __restrict__ B,
                                                 void* __restrict__ C0v,
                                                 void* __restrict__ C1v) {
    __shared__ __align__(16) us16 lA[2][BM * BK];   // 2 x 32 KiB
    __shared__ __align__(16) us16 lB[2][BN * BK];   // 2 x 32 KiB
    const int tid  = threadIdx.x;
    const int lane = tid & 63;
    const int w    = tid >> 6;          // 0..7
    const int wr   = w >> 2, wc = w & 3;
    const int l31  = lane & 31;
    const int lH   = lane >> 5;         // 0..1 (k-half within 16-k slot)

    // bijective XCD swizzle over nwg = 128*KSPLIT (multiple of 8)
    const int nwg = 128 * KSPLIT;
    const int qq  = nwg >> 3;
    const int bid = blockIdx.x;
    const int swz = (bid & 7) * qq + (bid >> 3);
    const int ks  = swz >> 7;
    const int rem = swz & 127;
    const int mT  = rem >> 4;           // 0..7
    const int nT  = rem & 15;           // 0..15
    const int KT  = (GK / KSPLIT) / BK;
    const size_t kbase = (size_t)ks * (GK / KSPLIT);

    // staging: per K-tile 8 gload_lds/thread (4 A + 4 B), 16B each
    size_t aOff[4], bOff[4];
    int ldsOff[4];
#pragma unroll
    for (int j = 0; j < 4; ++j) {
        int ch = j * 512 + tid;           // 0..2047 chunk id
        int rr = ch >> 3, cc = ch & 7;
        int sc = cc ^ (rr & 7);           // inverse-swizzled source col-chunk
        aOff[j] = (size_t)(mT * BM + rr) * GK + kbase + sc * 8;
        bOff[j] = (size_t)(nT * BN + rr) * GK + kbase + sc * 8;
        ldsOff[j] = (j * 512 + w * 64) * 8;  // wave-uniform linear dest
    }

    // fragment read bases: A rowblocks mr (32 rows each), B colblocks ncb
    int aBase[4], aX[4];
#pragma unroll
    for (int mr = 0; mr < 4; ++mr) {
        int r = wr * 128 + mr * 32 + l31;
        aBase[mr] = r * 64;   // halfs per LDS row = 64
        aX[mr]    = r & 7;
    }
    int bBase[2], bX[2];
#pragma unroll
    for (int ncb = 0; ncb < 2; ++ncb) {
        int r = wc * 64 + ncb * 32 + l31;
        bBase[ncb] = r * 64;
        bX[ncb]    = r & 7;
    }

    f32x16 acc[4][2] = {};   // [mr][ncb]

#define STAGE(t, buf) do { _Pragma("unroll") \
    for (int j = 0; j < 4; ++j) \
        __builtin_amdgcn_global_load_lds( \
            (const __attribute__((address_space(1))) void*)(A + aOff[j] + (size_t)(t) * BK), \
            (__attribute__((address_space(3))) void*)(&lA[buf][0] + ldsOff[j]), 16, 0, 0); \
    _Pragma("unroll") \
    for (int j = 0; j < 4; ++j) \
        __builtin_amdgcn_global_load_lds( \
            (const __attribute__((address_space(1))) void*)(B + bOff[j] + (size_t)(t) * BK), \
            (__attribute__((address_space(3))) void*)(&lB[buf][0] + ldsOff[j]), 16, 0, 0); \
    } while (0)

    // prologue: stage tiles 0 and 1
    STAGE(0, 0);
    STAGE(1, 1);
    __syncthreads();

    int cur = 0;
    for (int t = 0; t < KT; ++t) {
        const us16* pA = &lA[cur][0];
        const us16* pB = &lB[cur][0];

        // 4 k-slots of 16; per slot: 4 A-frags + 2 B-frags -> 8 MFMA
#pragma unroll
        for (int ks2 = 0; ks2 < 4; ++ks2) {
            const int c0 = ks2 * 2 + lH;   // nominal 16B chunk
            s16x8 af[4], bf[2];
#pragma unroll
            for (int mr = 0; mr < 4; ++mr)
                af[mr] = *reinterpret_cast<const s16x8*>(
                    pA + aBase[mr] + (c0 ^ aX[mr]) * 8);
#pragma unroll
            for (int ncb = 0; ncb < 2; ++ncb)
                bf[ncb] = *reinterpret_cast<const s16x8*>(
                    pB + bBase[ncb] + (c0 ^ bX[ncb]) * 8);
#pragma unroll
            for (int mr = 0; mr < 4; ++mr)
#pragma unroll
                for (int ncb = 0; ncb < 2; ++ncb)
                    acc[mr][ncb] = __builtin_amdgcn_mfma_f32_32x32x16_bf16(
                        af[mr], bf[ncb], acc[mr][ncb], 0, 0, 0);
        }

        // one barrier per K-tile: implicit vmcnt(0) drains tile-(t+1) stages
        // (issued a full K-tile ago) and fences all waves' reads of buf[cur].
        __syncthreads();

        if (t + 2 < KT) { STAGE(t + 2, cur); }
        cur ^= 1;
    }
#undef STAGE

    // C/D layout (32x32): col = lane&31, row = (reg&3)+8*(reg>>2)+4*(lane>>5)
    const int colB = nT * BN + wc * 64 + l31;
    const int rowB = mT * BM + wr * 128 + 4 * lH;
    if constexpr (KSPLIT == 2) {
        us16* C = (ks == 1) ? (us16*)C1v : (us16*)C0v;
#pragma unroll
        for (int mr = 0; mr < 4; ++mr)
#pragma unroll
            for (int ncb = 0; ncb < 2; ++ncb)
#pragma unroll
                for (int rg = 0; rg < 16; ++rg) {
                    int row = rowB + mr * 32 + (rg & 3) + 8 * (rg >> 2);
                    C[(size_t)row * OUTF + colB + ncb * 32] = f2bf(acc[mr][ncb][rg]);
                }
    } else {
        float* C = (float*)C0v;
#pragma unroll
        for (int mr = 0; mr < 4; ++mr)
#pragma unroll
            for (int ncb = 0; ncb < 2; ++ncb)
#pragma unroll
                for (int rg = 0; rg < 16; ++rg) {
                    int row = rowB + mr * 32 + (rg & 3) + 8 * (rg >> 2);
                    C[(size_t)row * OUTF + colB + ncb * 32] = acc[mr][ncb][rg];
                }
    }
}

// ---------------------------------------------------------------------------
// Kernel 3a: OUT = FWHT(bf16 Z0 + bf16 Z1) * (Wscale/64) * SV   (split path)
// ---------------------------------------------------------------------------
__global__ __launch_bounds__(256) void k_out_split(const us16* __restrict__ Z0,
                                                   const us16* __restrict__ Z1,
                                                   float* __restrict__ OUT,
                                                   const float* __restrict__ SV,
                                                   const float* __restrict__ wscale) {
    __shared__ float s[4096 + 256];
    const int row = blockIdx.x, t = threadIdx.x;
    const int hi = t >> 4, lo = t & 15;
    float v[16];
    const us16* zr0 = Z0 + (size_t)row * OUTF;
    const us16* zr1 = Z1 + (size_t)row * OUTF;

#pragma unroll
    for (int j = 0; j < 16; ++j)
        v[j] = bf2f(zr0[j * 256 + t]) + bf2f(zr1[j * 256 + t]);
    fwht16(v);
#pragma unroll
    for (int j = 0; j < 16; ++j) s[272 * j + 17 * hi + lo] = v[j];
    __syncthreads();

#pragma unroll
    for (int j = 0; j < 16; ++j) v[j] = s[272 * hi + 17 * j + lo];
    fwht16(v);
#pragma unroll
    for (int j = 0; j < 16; ++j) s[272 * hi + 17 * j + lo] = v[j];
    __syncthreads();

    const int base = 272 * hi + 17 * lo;
#pragma unroll
    for (int j = 0; j < 16; ++j) v[j] = s[base + j];
    fwht16(v);

    const float sc = wscale[0] * 0.015625f;
    const float4* sv4 = reinterpret_cast<const float4*>(SV + t * 16);
    float4* o4 = reinterpret_cast<float4*>(OUT + (size_t)row * OUTF + t * 16);
#pragma unroll
    for (int q = 0; q < 4; ++q) {
        float4 u = sv4[q];
        float4 o;
        o.x = v[q*4+0] * sc * u.x;
        o.y = v[q*4+1] * sc * u.y;
        o.z = v[q*4+2] * sc * u.z;
        o.w = v[q*4+3] * sc * u.w;
        o4[q] = o;
    }
}

// ---------------------------------------------------------------------------
// Kernel 3b: fallback, f32 Z in-place on d_out
// ---------------------------------------------------------------------------
__global__ __launch_bounds__(256) void k_out_single(float* __restrict__ Z,
                                                    const float* __restrict__ SV,
                                                    const float* __restrict__ wscale) {
    __shared__ float s[4096 + 256];
    const int row = blockIdx.x, t = threadIdx.x;
    const int hi = t >> 4, lo = t & 15;
    float v[16];
    float* zr = Z + (size_t)row * OUTF;

#pragma unroll
    for (int j = 0; j < 16; ++j) v[j] = zr[j * 256 + t];
    fwht16(v);
#pragma unroll
    for (int j = 0; j < 16; ++j) s[272 * j + 17 * hi + lo] = v[j];
    __syncthreads();

#pragma unroll
    for (int j = 0; j < 16; ++j) v[j] = s[272 * hi + 17 * j + lo];
    fwht16(v);
#pragma unroll
    for (int j = 0; j < 16; ++j) s[272 * hi + 17 * j + lo] = v[j];
    __syncthreads();

    const int base = 272 * hi + 17 * lo;
#pragma unroll
    for (int j = 0; j < 16; ++j) v[j] = s[base + j];
    fwht16(v);

    const float sc = wscale[0] * 0.015625f;
    const float4* sv4 = reinterpret_cast<const float4*>(SV + t * 16);
    float4* z4 = reinterpret_cast<float4*>(zr + t * 16);
#pragma unroll
    for (int q = 0; q < 4; ++q) {
        float4 u = sv4[q];
        float4 o;
        o.x = v[q*4+0] * sc * u.x;
        o.y = v[q*4+1] * sc * u.y;
        o.z = v[q*4+2] * sc * u.z;
        o.w = v[q*4+3] * sc * u.w;
        z4[q] = o;
    }
}

// ---------------------------------------------------------------------------
extern "C" void kernel_launch(void* const* d_in, const int* in_sizes, int n_in,
                              void* d_out, int out_size, void* d_ws, size_t ws_size,
                              hipStream_t stream) {
    const float* input  = (const float*)d_in[0];   // (2048, 4096) f32
    const int*   Qidxs  = (const int*)d_in[1];     // (4096, 512) i32
    const float* SU     = (const float*)d_in[2];   // (4096,) f32
    const float* SV     = (const float*)d_in[3];   // (4096,) f32
    const float* Wscale = (const float*)d_in[4];   // (1,) f32
    const void*  grid   = (const void*)d_in[9];    // (256, 8) grid_abs (dtype-probed)

    us16*  W  = (us16*)d_ws;                                       // 32 MB
    us16*  Y  = (us16*)((char*)d_ws + (size_t)32 * 1024 * 1024);   // 16 MB
    us16*  Z0 = (us16*)((char*)d_ws + (size_t)48 * 1024 * 1024);   // 16 MB (bf16)
    us16*  Z1 = (us16*)((char*)d_ws + (size_t)64 * 1024 * 1024);   // 16 MB (bf16)

    const bool split = ws_size >= (size_t)80 * 1024 * 1024;

    hipLaunchKernelGGL(k_pre, dim3(TOKENS + (OUTF * 512) / 256), dim3(256), 0, stream,
                       input, SU, Y, Qidxs, grid, W);
    if (split) {
        hipLaunchKernelGGL((k_gemm<2>), dim3(256), dim3(512), 0, stream,
                           Y, W, (void*)Z0, (void*)Z1);
        hipLaunchKernelGGL(k_out_split, dim3(TOKENS), dim3(256), 0, stream,
                           Z0, Z1, (float*)d_out, SV, Wscale);
    } else {
        hipLaunchKernelGGL((k_gemm<1>), dim3(128), dim3(512), 0, stream,
                           Y, W, d_out, d_out);
        hipLaunchKernelGGL(k_out_single, dim3(TOKENS), dim3(256), 0, stream,
                           (float*)d_out, SV, Wscale);
    }
}

// Round 10
// 121.925 us; speedup vs baseline: 1.0433x; 1.0433x over previous
//
#include <hip/hip_runtime.h>

typedef short s16;
typedef unsigned short us16;
typedef __attribute__((ext_vector_type(8))) short s16x8;
typedef __attribute__((ext_vector_type(8))) unsigned short u16x8;
typedef __attribute__((ext_vector_type(4))) float f32x4;

#define TOKENS 2048
#define INF    4096   // n_codes * 8
#define OUTF   4096   // m
#define GK     4096

// float -> bf16 round-to-nearest-even
__device__ __forceinline__ us16 f2bf(float f) {
    union { float f; unsigned u; } v; v.f = f;
    unsigned r = v.u + 0x7FFFu + ((v.u >> 16) & 1u);
    return (us16)(r >> 16);
}
__device__ __forceinline__ float bf2f(us16 u) {
    unsigned x = ((unsigned)u) << 16;
    float f; __builtin_memcpy(&f, &x, 4);
    return f;
}

// ---------------------------------------------------------------------------
// FWHT-16 fully in registers
// ---------------------------------------------------------------------------
__device__ __forceinline__ void fwht16(float v[16]) {
#pragma unroll
    for (int s = 1; s < 16; s <<= 1)
#pragma unroll
        for (int j = 0; j < 16; ++j)
            if (!(j & s)) {
                float a = v[j], b = v[j + s];
                v[j]     = a + b;
                v[j + s] = a - b;
            }
}

// ---------------------------------------------------------------------------
// Kernel 1 (merged): blocks [0,2048): y = bf16(FWHT(x*SU)/64)  (radix-16^3)
//                    blocks [2048, 10240): decompress E8P -> W (bf16)
// ---------------------------------------------------------------------------
__global__ __launch_bounds__(256) void k_pre(const float* __restrict__ X,
                                             const float* __restrict__ SU,
                                             us16* __restrict__ Y,
                                             const int* __restrict__ Q,
                                             const void* __restrict__ gridraw,
                                             us16* __restrict__ W) {
    __shared__ float s[4096 + 256];
    const int tid = threadIdx.x;

    if (blockIdx.x < TOKENS) {
        const int row = blockIdx.x;
        const int hi = tid >> 4, lo = tid & 15;
        float v[16];
        const float* xr = X + (size_t)row * INF;

#pragma unroll
        for (int j = 0; j < 16; ++j) v[j] = xr[j * 256 + tid] * SU[j * 256 + tid];
        fwht16(v);
#pragma unroll
        for (int j = 0; j < 16; ++j) s[272 * j + 17 * hi + lo] = v[j];
        __syncthreads();

#pragma unroll
        for (int j = 0; j < 16; ++j) v[j] = s[272 * hi + 17 * j + lo];
        fwht16(v);
#pragma unroll
        for (int j = 0; j < 16; ++j) s[272 * hi + 17 * j + lo] = v[j];
        __syncthreads();

        const int base = 272 * hi + 17 * lo;
#pragma unroll
        for (int j = 0; j < 16; ++j) v[j] = s[base + j];
        fwht16(v);

        s16x8 o0, o1;
#pragma unroll
        for (int j = 0; j < 8; ++j) {
            o0[j] = (s16)f2bf(v[j]     * 0.015625f);
            o1[j] = (s16)f2bf(v[j + 8] * 0.015625f);
        }
        s16x8* out = reinterpret_cast<s16x8*>(Y + (size_t)row * INF + tid * 16);
        out[0] = o0; out[1] = o1;
    } else {
        float (*gT)[256] = (float(*)[256])s;
        int* gOdd = (int*)(s + 2048);

        const unsigned short* gu = (const unsigned short*)gridraw;
        const float*          gf = (const float*)gridraw;
        const unsigned short  p0 = gu[0];

        float sum = 0.f;
#pragma unroll
        for (int j = 0; j < 8; ++j) {
            float v;
            if (p0 == 0x3800) {                       // float16
                unsigned short u = gu[tid * 8 + j];
                _Float16 hv; __builtin_memcpy(&hv, &u, 2);
                v = (float)hv;
            } else if (p0 == 0x3F00) {                // bfloat16
                v = bf2f(gu[tid * 8 + j]);
            } else {                                  // float32
                v = gf[tid * 8 + j];
            }
            gT[j][tid] = v;
            sum += v;
        }
        gOdd[tid] = ((int)(sum + 0.5f)) & 1;
        __syncthreads();

        const int code = (blockIdx.x - TOKENS) * 256 + tid;
        const int q        = Q[code];
        const int absIdx   = (q >> 8) & 255;
        const int signBits = (q >> 1) & 127;
        const float shift  = (q & 1) ? 0.25f : -0.25f;
        const int neg0 = (__popc(signBits) ^ gOdd[absIdx]) & 1;

        s16x8 o;
        o[0] = (s16)f2bf(gT[0][absIdx] * (1.0f - 2.0f * (float)neg0) + shift);
#pragma unroll
        for (int i = 1; i < 8; ++i) {
            float sg = 1.0f - 2.0f * (float)((signBits >> (i - 1)) & 1);
            o[i] = (s16)f2bf(gT[i][absIdx] * sg + shift);
        }
        *reinterpret_cast<s16x8*>(W + (size_t)code * 8) = o;
    }
}

// ---------------------------------------------------------------------------
// Kernel 2: GEMM  z[t][j] = sum_k y[t][k] * W[j][k]  (NT, K-major, bf16)
// 128x256 tile, BK=32, 8 waves (2Mx4N), wave tile 64x64, split-K templated.
// 48 KB LDS -> 2+ blocks/CU (cross-block MFMA||LDS||DMA overlap is the lever).
// mfma_f32_16x16x32_bf16, one MFMA consumes the full BK=32 depth.
// Single __syncthreads per K-tile (r6 structure), STAGE(t+2) after barrier.
// Swizzle: chunk c (0..3, 16B) XORed with (row>>1)&3 — with the row-parity
// bank bit this spreads 16-row fragment reads over all 32 banks (2-way, free).
// gload_lds(16B): linear LDS dest, inverse-swizzled global source.
// ---------------------------------------------------------------------------
#define BM 128
#define BN 256
#define BK 32

template<int KSPLIT>
__global__ __launch_bounds__(512, 4) void k_gemm(const us16* __restrict__ A,
                                                 const us16* __restrict__ B,
                                                 void* __restrict__ C0v,
                                                 void* __restrict__ C1v) {
    __shared__ __align__(16) us16 lA[2][BM * BK];   // 2 x 8 KiB
    __shared__ __align__(16) us16 lB[2][BN * BK];   // 2 x 16 KiB
    const int tid  = threadIdx.x;
    const int lane = tid & 63;
    const int w    = tid >> 6;          // 0..7
    const int wr   = w >> 2, wc = w & 3;
    const int laneRow = lane & 15, laneK = lane >> 4;   // laneK 0..3

    // bijective XCD swizzle over nwg = 256*KSPLIT (multiple of 8)
    const int nwg = 256 * KSPLIT;
    const int qq  = nwg >> 3;
    const int bid = blockIdx.x;
    const int swz = (bid & 7) * qq + (bid >> 3);
    const int ks  = swz >> 8;           // 0..KSPLIT-1
    const int rem = swz & 255;
    const int mT  = rem >> 4;           // 0..15
    const int nT  = rem & 15;           // 0..15
    const int KT  = (GK / KSPLIT) / BK; // 64 (split) / 128
    const size_t kbase = (size_t)ks * (GK / KSPLIT);

    // staging: A 512 chunks (1/thread), B 1024 chunks (2/thread), 16B each
    size_t aOff;
    {
        int rr = tid >> 2, cc = tid & 3;
        int sc = cc ^ ((rr >> 1) & 3);
        aOff = (size_t)(mT * BM + rr) * GK + kbase + sc * 8;
    }
    const int ldsOffA = (w * 64) * 8;       // wave-uniform halfs
    size_t bOff[2];
    int ldsOffB[2];
#pragma unroll
    for (int j = 0; j < 2; ++j) {
        int ch = j * 512 + tid;
        int rr = ch >> 2, cc = ch & 3;
        int sc = cc ^ ((rr >> 1) & 3);
        bOff[j] = (size_t)(nT * BN + rr) * GK + kbase + sc * 8;
        ldsOffB[j] = ((j * 512 + w * 64)) * 8;
    }

    // fragment read bases (halfs): row r -> r*32 + (laneK ^ ((r>>1)&3))*8
    int aB[4], aX[4], bB[4], bX[4];
#pragma unroll
    for (int mi = 0; mi < 4; ++mi) {
        int r = wr * 64 + mi * 16 + laneRow;
        aB[mi] = r * 32; aX[mi] = (r >> 1) & 3;
    }
#pragma unroll
    for (int nj = 0; nj < 4; ++nj) {
        int r = wc * 64 + nj * 16 + laneRow;
        bB[nj] = r * 32; bX[nj] = (r >> 1) & 3;
    }

    f32x4 acc[4][4] = {};   // [mi][nj]

#define STAGE(t, buf) do { const size_t _ko = (size_t)(t) * BK; \
    __builtin_amdgcn_global_load_lds( \
        (const __attribute__((address_space(1))) void*)(A + aOff + _ko), \
        (__attribute__((address_space(3))) void*)(&lA[buf][0] + ldsOffA), 16, 0, 0); \
    _Pragma("unroll") \
    for (int j = 0; j < 2; ++j) \
        __builtin_amdgcn_global_load_lds( \
            (const __attribute__((address_space(1))) void*)(B + bOff[j] + _ko), \
            (__attribute__((address_space(3))) void*)(&lB[buf][0] + ldsOffB[j]), 16, 0, 0); \
    } while (0)

    // prologue: stage tiles 0 and 1
    STAGE(0, 0);
    STAGE(1, 1);
    __syncthreads();

    int cur = 0;
    for (int t = 0; t < KT; ++t) {
        const us16* pA = &lA[cur][0];
        const us16* pB = &lB[cur][0];

        s16x8 af[4], bf[4];
#pragma unroll
        for (int mi = 0; mi < 4; ++mi)
            af[mi] = *reinterpret_cast<const s16x8*>(pA + aB[mi] + (laneK ^ aX[mi]) * 8);
#pragma unroll
        for (int nj = 0; nj < 4; ++nj)
            bf[nj] = *reinterpret_cast<const s16x8*>(pB + bB[nj] + (laneK ^ bX[nj]) * 8);

#pragma unroll
        for (int mi = 0; mi < 4; ++mi)
#pragma unroll
            for (int nj = 0; nj < 4; ++nj)
                acc[mi][nj] = __builtin_amdgcn_mfma_f32_16x16x32_bf16(
                    af[mi], bf[nj], acc[mi][nj], 0, 0, 0);

        // one barrier per K-tile: implicit vmcnt(0) drains tile-(t+1) stages
        // (issued a full K-tile ago) and fences all waves' reads of buf[cur].
        __syncthreads();

        if (t + 2 < KT) { STAGE(t + 2, cur); }
        cur ^= 1;
    }
#undef STAGE

    // C/D layout: col = lane&15, row = (lane>>4)*4 + reg
    const int colB = nT * BN + wc * 64 + laneRow;
    const int rowB = mT * BM + wr * 64 + laneK * 4;
    if constexpr (KSPLIT == 2) {
        us16* C = (ks == 1) ? (us16*)C1v : (us16*)C0v;
#pragma unroll
        for (int mi = 0; mi < 4; ++mi)
#pragma unroll
            for (int nj = 0; nj < 4; ++nj)
#pragma unroll
                for (int rg = 0; rg < 4; ++rg)
                    C[(size_t)(rowB + mi * 16 + rg) * OUTF + colB + nj * 16]
                        = f2bf(acc[mi][nj][rg]);
    } else {
        float* C = (float*)C0v;
#pragma unroll
        for (int mi = 0; mi < 4; ++mi)
#pragma unroll
            for (int nj = 0; nj < 4; ++nj)
#pragma unroll
                for (int rg = 0; rg < 4; ++rg)
                    C[(size_t)(rowB + mi * 16 + rg) * OUTF + colB + nj * 16]
                        = acc[mi][nj][rg];
    }
}

// ---------------------------------------------------------------------------
// Kernel 3a: OUT = FWHT(bf16 Z0 + bf16 Z1) * (Wscale/64) * SV   (split path)
// Digit-REORDERED radix-16^3: pass low digit (c) first on CONTIGUOUS us16x8
// loads (16B/lane), then digits b and a via padded LDS phys(e)=e+(e>>4).
// ---------------------------------------------------------------------------
__global__ __launch_bounds__(256) void k_out_split(const us16* __restrict__ Z0,
                                                   const us16* __restrict__ Z1,
                                                   float* __restrict__ OUT,
                                                   const float* __restrict__ SV,
                                                   const float* __restrict__ wscale) {
    __shared__ float s[4096 + 272];
    const int row = blockIdx.x, t = threadIdx.x;
    float v[16];
    const us16* zr0 = Z0 + (size_t)row * OUTF;
    const us16* zr1 = Z1 + (size_t)row * OUTF;

    // pass C (digit c): elements e = t*16 + j, contiguous 32B/array
    {
        u16x8 a0 = reinterpret_cast<const u16x8*>(zr0 + t * 16)[0];
        u16x8 a1 = reinterpret_cast<const u16x8*>(zr0 + t * 16)[1];
        u16x8 b0 = reinterpret_cast<const u16x8*>(zr1 + t * 16)[0];
        u16x8 b1 = reinterpret_cast<const u16x8*>(zr1 + t * 16)[1];
#pragma unroll
        for (int j = 0; j < 8; ++j) {
            v[j]     = bf2f(a0[j]) + bf2f(b0[j]);
            v[j + 8] = bf2f(a1[j]) + bf2f(b1[j]);
        }
    }
    fwht16(v);
    // store phys(t*16+j) = 17*t + j
#pragma unroll
    for (int j = 0; j < 16; ++j) s[17 * t + j] = v[j];
    __syncthreads();

    // pass B (digit b): thread (a0=t>>4, c0=t&15); phys = 272*a0 + 17*j + c0
    const int pa = 272 * (t >> 4) + (t & 15);
#pragma unroll
    for (int j = 0; j < 16; ++j) v[j] = s[pa + 17 * j];
    fwht16(v);
#pragma unroll
    for (int j = 0; j < 16; ++j) s[pa + 17 * j] = v[j];
    __syncthreads();

    // pass A (digit a): thread (b0=t>>4, c0=t&15); phys = 272*j + 17*b0 + c0
    const int pb = 17 * (t >> 4) + (t & 15);
#pragma unroll
    for (int j = 0; j < 16; ++j) v[j] = s[272 * j + pb];
    fwht16(v);

    const float sc = wscale[0] * 0.015625f;
    float* orow = OUT + (size_t)row * OUTF;
#pragma unroll
    for (int j = 0; j < 16; ++j)
        orow[j * 256 + t] = v[j] * sc * SV[j * 256 + t];
}

// ---------------------------------------------------------------------------
// Kernel 3b: fallback, f32 Z in-place on d_out (original digit order)
// ---------------------------------------------------------------------------
__global__ __launch_bounds__(256) void k_out_single(float* __restrict__ Z,
                                                    const float* __restrict__ SV,
                                                    const float* __restrict__ wscale) {
    __shared__ float s[4096 + 272];
    const int row = blockIdx.x, t = threadIdx.x;
    const int hi = t >> 4, lo = t & 15;
    float v[16];
    float* zr = Z + (size_t)row * OUTF;

#pragma unroll
    for (int j = 0; j < 16; ++j) v[j] = zr[j * 256 + t];
    fwht16(v);
#pragma unroll
    for (int j = 0; j < 16; ++j) s[272 * j + 17 * hi + lo] = v[j];
    __syncthreads();

#pragma unroll
    for (int j = 0; j < 16; ++j) v[j] = s[272 * hi + 17 * j + lo];
    fwht16(v);
#pragma unroll
    for (int j = 0; j < 16; ++j) s[272 * hi + 17 * j + lo] = v[j];
    __syncthreads();

    const int base = 272 * hi + 17 * lo;
#pragma unroll
    for (int j = 0; j < 16; ++j) v[j] = s[base + j];
    fwht16(v);

    const float sc = wscale[0] * 0.015625f;
    const float4* sv4 = reinterpret_cast<const float4*>(SV + t * 16);
    float4* z4 = reinterpret_cast<float4*>(zr + t * 16);
#pragma unroll
    for (int q = 0; q < 4; ++q) {
        float4 u = sv4[q];
        float4 o;
        o.x = v[q*4+0] * sc * u.x;
        o.y = v[q*4+1] * sc * u.y;
        o.z = v[q*4+2] * sc * u.z;
        o.w = v[q*4+3] * sc * u.w;
        z4[q] = o;
    }
}

// ---------------------------------------------------------------------------
extern "C" void kernel_launch(void* const* d_in, const int* in_sizes, int n_in,
                              void* d_out, int out_size, void* d_ws, size_t ws_size,
                              hipStream_t stream) {
    const float* input  = (const float*)d_in[0];   // (2048, 4096) f32
    const int*   Qidxs  = (const int*)d_in[1];     // (4096, 512) i32
    const float* SU     = (const float*)d_in[2];   // (4096,) f32
    const float* SV     = (const float*)d_in[3];   // (4096,) f32
    const float* Wscale = (const float*)d_in[4];   // (1,) f32
    const void*  grid   = (const void*)d_in[9];    // (256, 8) grid_abs (dtype-probed)

    us16*  W  = (us16*)d_ws;                                       // 32 MB
    us16*  Y  = (us16*)((char*)d_ws + (size_t)32 * 1024 * 1024);   // 16 MB
    us16*  Z0 = (us16*)((char*)d_ws + (size_t)48 * 1024 * 1024);   // 16 MB (bf16)
    us16*  Z1 = (us16*)((char*)d_ws + (size_t)64 * 1024 * 1024);   // 16 MB (bf16)

    const bool split = ws_size >= (size_t)80 * 1024 * 1024;

    hipLaunchKernelGGL(k_pre, dim3(TOKENS + (OUTF * 512) / 256), dim3(256), 0, stream,
                       input, SU, Y, Qidxs, grid, W);
    if (split) {
        hipLaunchKernelGGL((k_gemm<2>), dim3(512), dim3(512), 0, stream,
                           Y, W, (void*)Z0, (void*)Z1);
        hipLaunchKernelGGL(k_out_split, dim3(TOKENS), dim3(256), 0, stream,
                           Z0, Z1, (float*)d_out, SV, Wscale);
    } else {
        hipLaunchKernelGGL((k_gemm<1>), dim3(256), dim3(512), 0, stream,
                           Y, W, d_out, d_out);
        hipLaunchKernelGGL(k_out_single, dim3(TOKENS), dim3(256), 0, stream,
                           (float*)d_out, SV, Wscale);
    }
}